// Round 11
// baseline (156.505 us; speedup 1.0000x reference)
//
#include <hip/hip_runtime.h>

typedef float f32x4 __attribute__((ext_vector_type(4)));
typedef float f32x2 __attribute__((ext_vector_type(2)));
typedef short bf16x8 __attribute__((ext_vector_type(8)));
typedef short s16x4 __attribute__((ext_vector_type(4)));

#define N_TOT 8192
#define L_OBS 20
#define P_PRED 30
#define E_DIM 64
#define H_DIM 128
#define C_DIM 2048
#define G_DIM 512
#define M_ROWS 32
#define NTH 1024
#define A_PAD 200   // bf16 elems per A row (400 B rows, 16B aligned)

#define K1 1.442695041f
#define K2 2.885390082f

static __device__ __forceinline__ unsigned short f2bf(float f) {
  union { float f; unsigned int u; } v; v.f = f;
  unsigned int u = v.u;
  return (unsigned short)((u + 0x7FFFu + ((u >> 16) & 1u)) >> 16);
}
static __device__ __forceinline__ float bf2f(unsigned short b) {
  union { unsigned int u; float f; } v; v.u = ((unsigned int)b) << 16;
  return v.f;
}
static __device__ __forceinline__ float ex2(float x)  { float r; asm("v_exp_f32 %0, %1" : "=v"(r) : "v"(x)); return r; }
static __device__ __forceinline__ float rcpn(float x) { float r; asm("v_rcp_f32 %0, %1" : "=v"(r) : "v"(x)); return r; }
static __device__ __forceinline__ unsigned int cvtpk(float lo, float hi) {
  unsigned int r; asm("v_cvt_pk_bf16_f32 %0, %1, %2" : "=v"(r) : "v"(lo), "v"(hi)); return r;
}

// 1024 threads, 158 KB LDS -> hardware fits exactly ONE block/CU -> 4 waves/SIMD
// is the max occupancy, so the compiler budgets 128 VGPR (min 4 waves/EU declared).
// W_hh lives in LDS (pre-swizzled fragments); only W_ih (16 regs) stays in registers.
__global__ __launch_bounds__(NTH, 4)
void lstm_traj(const float* __restrict__ img,      // [N][C]
               const float* __restrict__ obs_pos,  // [N][L][2]
               const float* __restrict__ obs_rel,  // [N][L][2]
               const int*   __restrict__ hist,     // [N]
               const float* __restrict__ h0,       // [H]
               const float* __restrict__ W_embed,  // [2][E]
               const float* __restrict__ b_embed,  // [E]
               const float* __restrict__ W_ih,     // [E][4H]
               const float* __restrict__ W_hh,     // [H][4H]
               const float* __restrict__ b_ih,     // [4H]
               const float* __restrict__ b_hh,     // [4H]
               const float* __restrict__ W_pred,   // [H+C][2]
               const float* __restrict__ b_pred,   // [2]
               float* __restrict__ out)            // [N][P][2]
{
  __shared__ unsigned short A_lds[2][M_ROWS][A_PAD];   // 25.6 KB
  __shared__ unsigned short Whh_lds[16 * 2 * 4 * 64 * 8]; // 128 KB: [wave][T][ks][lane][8]
  __shared__ float We_lds[2][E_DIM];
  __shared__ float be_lds[E_DIM];
  __shared__ float Wp_lds[H_DIM][2];

  const int t    = threadIdx.x;
  const int w    = t >> 6;        // wave 0..15: owns units w*8..w*8+7 (x 4 gates = 32 cols)
  const int l    = t & 63;
  const int u15  = l & 15;        // MFMA A-row / D-col index
  const int rq   = l >> 4;        // MFMA k-group / row-quad
  const int hi   = u15 >> 3;      // 0: lane holds gates i,g ; 1: gates f,o ; processes rt=hi rows
  const int myu  = w * 8 + (u15 & 7);  // owned hidden unit
  const int wg0  = blockIdx.x * M_ROWS;
  const int grow = t >> 5;        // 0..31: row for e/rel/img work
  const int c2   = t & 31;        // 0..31: slot within row group

  const float* relrow = obs_rel + (wg0 + grow) * (L_OBS * 2);

  // ---- stage small weights to LDS ----
  if (t < 128) We_lds[t >> 6][t & 63] = W_embed[t];
  if (t < 64)  be_lds[t] = b_embed[t];
  if (t >= 128 && t < 384) ((float*)Wp_lds)[t - 128] = W_pred[t - 128];

  // ---- stage W_hh into LDS, pre-swizzled to per-wave fragment layout ----
  // fragment set fs = ((wv*2+T)*4+ks)*64 + lane ; elements i: W_hh[ks*32+rq*8+i][gcol]
#pragma unroll
  for (int j = 0; j < 8; ++j) {
    const int fs    = t * 8 + j;
    const int lane_ = fs & 63;
    const int ks_   = (fs >> 6) & 3;
    const int T_    = (fs >> 8) & 1;
    const int wv_   = fs >> 9;
    const int rq_   = lane_ >> 4;
    const int u15_  = lane_ & 15;
    const int col   = (T_ * 2 + (u15_ >> 3)) * 128 + wv_ * 8 + (u15_ & 7);
    bf16x8 v8;
#pragma unroll
    for (int i = 0; i < 8; ++i) {
      const int k = ks_ * 32 + rq_ * 8 + i;
      v8[i] = (short)f2bf(W_hh[k * G_DIM + col]);
    }
    *(bf16x8*)&Whh_lds[fs * 8] = v8;
  }

  // ---- W_ih fragments in registers (ks 0..1 only): 4 frags = 16 VGPR ----
  bf16x8 Bih[2][2];
#pragma unroll
  for (int T = 0; T < 2; ++T) {
    const int gcol = (T * 2 + hi) * 128 + myu;
#pragma unroll
    for (int ks = 0; ks < 2; ++ks)
#pragma unroll
      for (int i = 0; i < 8; ++i) {
        const int k = ks * 32 + rq * 8 + i;
        Bih[T][ks][i] = (short)f2bf(W_ih[k * G_DIM + gcol]);
      }
  }

  // per-wave W_hh fragment base: frag(T,ks) at whbase + (T*4+ks)*512
  const unsigned short* whbase = &Whh_lds[(w * 8) * 512 + l * 8];

  // ---- log2e-scaled negative biases for all 4 gates of myu ----
  const float nbi = -K1 * (b_ih[myu]       + b_hh[myu]);
  const float nbf = -K1 * (b_ih[128 + myu] + b_hh[128 + myu]);
  const float nbg = -K2 * (b_ih[256 + myu] + b_hh[256 + myu]);
  const float nbo = -K1 * (b_ih[384 + myu] + b_hh[384 + myu]);

  // ---- per-lane state: unit myu, rows hi*16 + rq*4 + q ----
  const float h0u = h0[myu];
  const unsigned short h0b = f2bf(h0u);
  float cs[4], hreg[4];
  int sact = 0;
#pragma unroll
  for (int q = 0; q < 4; ++q) {
    const int row = hi * 16 + rq * 4 + q;
    cs[q] = h0u; hreg[q] = h0u;
    sact |= ((20 - hist[wg0 + row]) & 255) << (8 * q);
    A_lds[0][row][64 + myu] = h0b;
  }

  // WG-uniform first-active step
  int mn = 20;
#pragma unroll
  for (int q = 0; q < 4; ++q) { const int sa = (sact >> (8 * q)) & 255; mn = sa < mn ? sa : mn; }
  { int o = __shfl_xor(mn, 8);  mn = o < mn ? o : mn; }
  { int o = __shfl_xor(mn, 16); mn = o < mn ? o : mn; }
  { int o = __shfl_xor(mn, 32); mn = o < mn ? o : mn; }
  const int s_min = __builtin_amdgcn_readfirstlane(mn < 1 ? 1 : mn);

  __syncthreads();  // We/be/Wp/Whh staged

  // ---- e for first active obs step ----
  if (s_min <= L_OBS - 2) {
    const f32x2 rr = *(const f32x2*)(relrow + (s_min + 1) * 2);
    const int j = c2 * 2;
    const float e0 = fmaxf(fmaf(rr.x, We_lds[0][j],     fmaf(rr.y, We_lds[1][j],     be_lds[j])),     0.f);
    const float e1 = fmaxf(fmaf(rr.x, We_lds[0][j + 1], fmaf(rr.y, We_lds[1][j + 1], be_lds[j + 1])), 0.f);
    *(unsigned int*)&A_lds[0][grow][j] = cvtpk(e0, e1);
  }

  // ---- pos init + img_proj (32 lanes per row, coalesced float4) ----
  float pos0 = obs_pos[(wg0 + grow) * (L_OBS * 2) + (L_OBS - 1) * 2];
  float pos1 = obs_pos[(wg0 + grow) * (L_OBS * 2) + (L_OBS - 1) * 2 + 1];
  float ip0 = 0.f, ip1 = 0.f;
  {
    const float* irow = img + (long)(wg0 + grow) * C_DIM;
#pragma unroll 4
    for (int i = 0; i < 16; ++i) {
      const int k0 = i * 128 + c2 * 4;
      const f32x4 v  = *(const f32x4*)(irow + k0);
      const f32x4 wa = *(const f32x4*)(W_pred + (H_DIM + k0) * 2);
      const f32x4 wb = *(const f32x4*)(W_pred + (H_DIM + k0) * 2 + 4);
      ip0 = fmaf(v.x, wa.x, fmaf(v.y, wa.z, fmaf(v.z, wb.x, fmaf(v.w, wb.z, ip0))));
      ip1 = fmaf(v.x, wa.y, fmaf(v.y, wa.w, fmaf(v.z, wb.y, fmaf(v.w, wb.w, ip1))));
    }
#pragma unroll
    for (int m = 16; m >= 1; m >>= 1) { ip0 += __shfl_xor(ip0, m); ip1 += __shfl_xor(ip1, m); }
    ip0 += b_pred[0]; ip1 += b_pred[1];
  }
  __syncthreads();  // A_lds[0] ready

  int cur = 0;

  // exchange + gates + h-write (r10-proven). acc[rt][T] = gate (T*2+hi), rows rt*16+rq*4+q.
  auto gates_and_h = [&](f32x4 (&acc)[2][2], int nxt_, int s_, bool domask) {
    f32x4 rx[2];
#pragma unroll
    for (int T = 0; T < 2; ++T)
#pragma unroll
      for (int q = 0; q < 4; ++q) {
        const float src = hi ? acc[0][T][q] : acc[1][T][q];
        rx[T][q] = __shfl_xor(src, 8);
      }
#pragma unroll
    for (int q = 0; q < 4; ++q) {
      const float iv = hi ? rx[0][q]     : acc[0][0][q];
      const float fv = hi ? acc[1][0][q] : rx[0][q];
      const float gv = hi ? rx[1][q]     : acc[0][1][q];
      const float ov = hi ? acc[1][1][q] : rx[1][q];
      const float A_ = ex2(fmaf(iv, -K1, nbi));
      const float F_ = ex2(fmaf(fv, -K1, nbf));
      const float B_ = ex2(fmaf(gv, -K2, nbg));
      const float C_ = ex2(fmaf(ov, -K1, nbo));
      const float P2 = 1.f + B_;
      const float PB = (1.f + A_) * P2;
      const float Q  = 1.f + F_;
      const float cn = fmaf(cs[q], PB, (2.f - P2) * Q) * rcpn(PB * Q);
      const float cc = fmaxf(fminf(cn, 40.f), -40.f);
      const float D_ = ex2(-K2 * cc);
      const float hn = (1.f - D_) * rcpn((1.f + D_) * (1.f + C_)); // tanh(cn)*sigmoid(o)
      bool act = true;
      if (domask) act = s_ >= ((sact >> (8 * q)) & 255);
      if (act) { cs[q] = cn; hreg[q] = hn; }
    }
    const unsigned int p01 = cvtpk(hreg[0], hreg[1]);
    const unsigned int p23 = cvtpk(hreg[2], hreg[3]);
    const int rowb = hi * 16 + rq * 4;
    A_lds[nxt_][rowb + 0][64 + myu] = (unsigned short)p01;
    A_lds[nxt_][rowb + 1][64 + myu] = (unsigned short)(p01 >> 16);
    A_lds[nxt_][rowb + 2][64 + myu] = (unsigned short)p23;
    A_lds[nxt_][rowb + 3][64 + myu] = (unsigned short)(p23 >> 16);
  };

  // ================= obs phase: steps s_min..18 =================
#pragma unroll 1
  for (int s = s_min; s < L_OBS - 1; ++s) {
    const int nxt = cur ^ 1;
    const int sN = (s + 2 <= L_OBS - 1) ? (s + 2) : (L_OBS - 1);
    const f32x2 rrN = *(const f32x2*)(relrow + sN * 2);

    f32x4 acc[2][2];
#pragma unroll
    for (int rt = 0; rt < 2; ++rt)
#pragma unroll
      for (int T = 0; T < 2; ++T) { acc[rt][T].x = 0.f; acc[rt][T].y = 0.f; acc[rt][T].z = 0.f; acc[rt][T].w = 0.f; }
#pragma unroll
    for (int ks = 0; ks < 6; ++ks) {
      bf16x8 b0, b1;
      if (ks < 2) { b0 = Bih[0][ks]; b1 = Bih[1][ks]; }
      else {
        b0 = *(const bf16x8*)(whbase + (0 * 4 + (ks - 2)) * 512);
        b1 = *(const bf16x8*)(whbase + (1 * 4 + (ks - 2)) * 512);
      }
#pragma unroll
      for (int rt = 0; rt < 2; ++rt) {
        const bf16x8 a = *(const bf16x8*)&A_lds[cur][rt * 16 + u15][ks * 32 + rq * 8];
        acc[rt][0] = __builtin_amdgcn_mfma_f32_16x16x32_bf16(a, b0, acc[rt][0], 0, 0, 0);
        acc[rt][1] = __builtin_amdgcn_mfma_f32_16x16x32_bf16(a, b1, acc[rt][1], 0, 0, 0);
      }
    }

    // next-step e into A[nxt] (fills MFMA shadow)
    {
      const int j = c2 * 2;
      const float e0 = fmaxf(fmaf(rrN.x, We_lds[0][j],     fmaf(rrN.y, We_lds[1][j],     be_lds[j])),     0.f);
      const float e1 = fmaxf(fmaf(rrN.x, We_lds[0][j + 1], fmaf(rrN.y, We_lds[1][j + 1], be_lds[j + 1])), 0.f);
      *(unsigned int*)&A_lds[nxt][grow][j] = cvtpk(e0, e1);
    }

    gates_and_h(acc, nxt, s, true);
    cur = nxt;
    __syncthreads();
  }

  // ================= pred phase: 30 steps =================
#pragma unroll 1
  for (int p = 0; p < P_PRED; ++p) {
    const bool last = (p == P_PRED - 1);

    // rel chain: hv read + per-lane partial dot (4 units)
    const s16x4 hv = *(const s16x4*)&A_lds[cur][grow][64 + c2 * 4];
    float s0 = 0.f, s1 = 0.f;
#pragma unroll
    for (int i = 0; i < 4; ++i) {
      const float hfv = bf2f((unsigned short)hv[i]);
      s0 = fmaf(hfv, Wp_lds[c2 * 4 + i][0], s0);
      s1 = fmaf(hfv, Wp_lds[c2 * 4 + i][1], s1);
    }

    // h-part MFMAs (W_hh frags from LDS); overlap the shuffle tree
    f32x4 acc[2][2];
#pragma unroll
    for (int rt = 0; rt < 2; ++rt)
#pragma unroll
      for (int T = 0; T < 2; ++T) { acc[rt][T].x = 0.f; acc[rt][T].y = 0.f; acc[rt][T].z = 0.f; acc[rt][T].w = 0.f; }
    if (!last) {
#pragma unroll
      for (int ks4 = 0; ks4 < 4; ++ks4) {
        const bf16x8 b0 = *(const bf16x8*)(whbase + (0 * 4 + ks4) * 512);
        const bf16x8 b1 = *(const bf16x8*)(whbase + (1 * 4 + ks4) * 512);
#pragma unroll
        for (int rt = 0; rt < 2; ++rt) {
          const bf16x8 a = *(const bf16x8*)&A_lds[cur][rt * 16 + u15][64 + ks4 * 32 + rq * 8];
          acc[rt][0] = __builtin_amdgcn_mfma_f32_16x16x32_bf16(a, b0, acc[rt][0], 0, 0, 0);
          acc[rt][1] = __builtin_amdgcn_mfma_f32_16x16x32_bf16(a, b1, acc[rt][1], 0, 0, 0);
        }
      }
    }

    // finish rel reduction (within 32-lane row group)
#pragma unroll
    for (int m = 16; m >= 1; m >>= 1) { s0 += __shfl_xor(s0, m); s1 += __shfl_xor(s1, m); }
    const float rel0 = s0 + ip0, rel1 = s1 + ip1;
    pos0 += rel0; pos1 += rel1;
    if (c2 == 0) {
      float2 o; o.x = pos0; o.y = pos1;
      *(float2*)&out[((long)(wg0 + grow) * P_PRED + p) * 2] = o;
    }
    if (last) break;

    // e = relu(rel @ W_embed + b_embed) into A[cur] cols 0..63
    {
      const int j = c2 * 2;
      const float e0 = fmaxf(fmaf(rel0, We_lds[0][j],     fmaf(rel1, We_lds[1][j],     be_lds[j])),     0.f);
      const float e1 = fmaxf(fmaf(rel0, We_lds[0][j + 1], fmaf(rel1, We_lds[1][j + 1], be_lds[j + 1])), 0.f);
      *(unsigned int*)&A_lds[cur][grow][j] = cvtpk(e0, e1);
    }
    __syncthreads();  // barrier B: e visible

    // e-part MFMAs (ks 0..1, W_ih regs)
#pragma unroll
    for (int ks = 0; ks < 2; ++ks)
#pragma unroll
      for (int rt = 0; rt < 2; ++rt) {
        const bf16x8 a = *(const bf16x8*)&A_lds[cur][rt * 16 + u15][ks * 32 + rq * 8];
        acc[rt][0] = __builtin_amdgcn_mfma_f32_16x16x32_bf16(a, Bih[0][ks], acc[rt][0], 0, 0, 0);
        acc[rt][1] = __builtin_amdgcn_mfma_f32_16x16x32_bf16(a, Bih[1][ks], acc[rt][1], 0, 0, 0);
      }

    const int nxt = cur ^ 1;
    gates_and_h(acc, nxt, 0, false);
    cur = nxt;
    __syncthreads();  // barrier A: h visible
  }
}

extern "C" void kernel_launch(void* const* d_in, const int* in_sizes, int n_in,
                              void* d_out, int out_size, void* d_ws, size_t ws_size,
                              hipStream_t stream) {
  (void)in_sizes; (void)n_in; (void)out_size; (void)d_ws; (void)ws_size;
  lstm_traj<<<dim3(N_TOT / M_ROWS), dim3(NTH), 0, stream>>>(
      (const float*)d_in[0],  // img_embedding
      (const float*)d_in[1],  // obs_pos
      (const float*)d_in[2],  // obs_pos_rel
      (const int*)  d_in[3],  // obs_hist_size
      (const float*)d_in[4],  // h0
      (const float*)d_in[5],  // W_embed
      (const float*)d_in[6],  // b_embed
      (const float*)d_in[7],  // W_ih
      (const float*)d_in[8],  // W_hh
      (const float*)d_in[9],  // b_ih
      (const float*)d_in[10], // b_hh
      (const float*)d_in[11], // W_pred
      (const float*)d_in[12], // b_pred
      (float*)d_out);
}

// Round 12
// 143.149 us; speedup vs baseline: 1.0933x; 1.0933x over previous
//
#include <hip/hip_runtime.h>

typedef float f32x4 __attribute__((ext_vector_type(4)));
typedef float f32x2 __attribute__((ext_vector_type(2)));
typedef short bf16x8 __attribute__((ext_vector_type(8)));
typedef short s16x4 __attribute__((ext_vector_type(4)));

#define N_TOT 8192
#define L_OBS 20
#define P_PRED 30
#define E_DIM 64
#define H_DIM 128
#define C_DIM 2048
#define G_DIM 512
#define NTH 512
#define A_PAD 200
#define K_OBS 18          // obs steps k=0..17 ; pred steps k=18..47
#define NSTEP 48

#define K1 1.442695041f
#define K2 2.885390082f

static __device__ __forceinline__ unsigned short f2bf(float f) {
  union { float f; unsigned int u; } v; v.f = f;
  unsigned int u = v.u;
  return (unsigned short)((u + 0x7FFFu + ((u >> 16) & 1u)) >> 16);
}
static __device__ __forceinline__ float bf2f(unsigned short b) {
  union { unsigned int u; float f; } v; v.u = ((unsigned int)b) << 16;
  return v.f;
}
static __device__ __forceinline__ float ex2(float x)  { float r; asm("v_exp_f32 %0, %1" : "=v"(r) : "v"(x)); return r; }
static __device__ __forceinline__ float rcpn(float x) { float r; asm("v_rcp_f32 %0, %1" : "=v"(r) : "v"(x)); return r; }
static __device__ __forceinline__ unsigned int cvtpk(float lo, float hi) {
  unsigned int r; asm("v_cvt_pk_bf16_f32 %0, %1, %2" : "=v"(r) : "v"(lo), "v"(hi)); return r;
}

__global__ __launch_bounds__(NTH, 2)
void lstm_traj(const float* __restrict__ img,      // [N][C]
               const float* __restrict__ obs_pos,  // [N][L][2]
               const float* __restrict__ obs_rel,  // [N][L][2]
               const int*   __restrict__ hist,     // [N]
               const float* __restrict__ h0,       // [H]
               const float* __restrict__ W_embed,  // [2][E]
               const float* __restrict__ b_embed,  // [E]
               const float* __restrict__ W_ih,     // [E][4H]
               const float* __restrict__ W_hh,     // [H][4H]
               const float* __restrict__ b_ih,     // [4H]
               const float* __restrict__ b_hh,     // [4H]
               const float* __restrict__ W_pred,   // [H+C][2]
               const float* __restrict__ b_pred,   // [2]
               float* __restrict__ out)            // [N][P][2]
{
  // Two independent row-groups of 16, each double-buffered: [group][buf][row][e|h]
  __shared__ unsigned short A_lds[2][2][16][A_PAD];   // 25.6 KB
  __shared__ float We_lds[2][E_DIM];
  __shared__ float be_lds[E_DIM];
  __shared__ float Wp_lds[H_DIM][2];
  __shared__ float ip_lds[32][2];

  const int t     = threadIdx.x;
  const int w     = t >> 6;
  const int l     = t & 63;
  const int u15   = l & 15;        // MFMA A-row / D-col
  const int rq    = l >> 4;        // k-group / row-quad
  const int u     = w * 16 + u15;  // owned hidden unit (per gate)
  const int wg0   = blockIdx.x * 32;
  const int grow  = t >> 5;        // 0..15 row within group (for rel/e work)
  const int c2    = t & 31;        // slot within row
  const int row32 = t >> 4;        // 0..31 (prologue: both groups)
  const int gj    = t & 15;

  // ---- stage small weights ----
  if (t < 128) We_lds[t >> 6][t & 63] = W_embed[t];
  if (t < 64)  be_lds[t] = b_embed[t];
  if (t >= 128 && t < 384) ((float*)Wp_lds)[t - 128] = W_pred[t - 128];
  __syncthreads();

  // ---- B fragments (all 4 gates of 16 units per wave): 24 frags = 96 VGPR ----
  bf16x8 B[4][6];
#pragma unroll
  for (int ks = 0; ks < 6; ++ks)
#pragma unroll
    for (int i = 0; i < 8; ++i) {
      const int k = ks * 32 + rq * 8 + i;
      const float* Wrow = (k < E_DIM) ? (W_ih + k * G_DIM) : (W_hh + (k - E_DIM) * G_DIM);
#pragma unroll
      for (int gt = 0; gt < 4; ++gt)
        B[gt][ks][i] = (short)f2bf(Wrow[gt * 128 + u]);
    }

  const float nbi = -K1 * (b_ih[u]       + b_hh[u]);
  const float nbf = -K1 * (b_ih[128 + u] + b_hh[128 + u]);
  const float nbg = -K2 * (b_ih[256 + u] + b_hh[256 + u]);
  const float nbo = -K1 * (b_ih[384 + u] + b_hh[384 + u]);

  // ---- per-group state: rows rq*4+q, unit u ----
  const float h0u = h0[u];
  const unsigned short h0b = f2bf(h0u);
  float cs0[4], cs1[4], hp0[4], hp1[4];
  int sact0 = 0, sact1 = 0;   // thr = 19 - hist ; gates act iff k >= thr
#pragma unroll
  for (int q = 0; q < 4; ++q) {
    const int row = rq * 4 + q;
    cs0[q] = h0u; hp0[q] = h0u;
    cs1[q] = h0u; hp1[q] = h0u;
    sact0 |= ((19 - hist[wg0 + row])      & 255) << (8 * q);
    sact1 |= ((19 - hist[wg0 + 16 + row]) & 255) << (8 * q);
    A_lds[0][0][row][64 + u] = h0b;
    A_lds[1][0][row][64 + u] = h0b;
  }

  // ---- e for step 0 (obs_rel[:,2,:]) for both groups ----
  {
    const f32x2 rr = *(const f32x2*)(obs_rel + (wg0 + row32) * (L_OBS * 2) + 4);
    const int j = gj * 4;
    const float e0 = fmaxf(fmaf(rr.x, We_lds[0][j],     fmaf(rr.y, We_lds[1][j],     be_lds[j])),     0.f);
    const float e1 = fmaxf(fmaf(rr.x, We_lds[0][j + 1], fmaf(rr.y, We_lds[1][j + 1], be_lds[j + 1])), 0.f);
    const float e2 = fmaxf(fmaf(rr.x, We_lds[0][j + 2], fmaf(rr.y, We_lds[1][j + 2], be_lds[j + 2])), 0.f);
    const float e3 = fmaxf(fmaf(rr.x, We_lds[0][j + 3], fmaf(rr.y, We_lds[1][j + 3], be_lds[j + 3])), 0.f);
    uint2 pk; pk.x = cvtpk(e0, e1); pk.y = cvtpk(e2, e3);
    *(uint2*)&A_lds[row32 >> 4][0][row32 & 15][j] = pk;
  }

  // ---- img_proj for 32 rows -> ip_lds ----
  {
    float ig0 = 0.f, ig1 = 0.f;
    const float* irow = img + (long)(wg0 + row32) * C_DIM;
#pragma unroll 4
    for (int i = 0; i < 32; ++i) {
      const int k0 = i * 64 + gj * 4;
      const f32x4 v  = *(const f32x4*)(irow + k0);
      const f32x4 wa = *(const f32x4*)(W_pred + (H_DIM + k0) * 2);
      const f32x4 wb = *(const f32x4*)(W_pred + (H_DIM + k0) * 2 + 4);
      ig0 = fmaf(v.x, wa.x, fmaf(v.y, wa.z, fmaf(v.z, wb.x, fmaf(v.w, wb.z, ig0))));
      ig1 = fmaf(v.x, wa.y, fmaf(v.y, wa.w, fmaf(v.z, wb.y, fmaf(v.w, wb.w, ig1))));
    }
#pragma unroll
    for (int m = 8; m >= 1; m >>= 1) { ig0 += __shfl_xor(ig0, m); ig1 += __shfl_xor(ig1, m); }
    if (gj == 0) { ip_lds[row32][0] = ig0 + b_pred[0]; ip_lds[row32][1] = ig1 + b_pred[1]; }
  }

  float posA0 = obs_pos[(wg0 + grow) * (L_OBS * 2) + 38];
  float posA1 = obs_pos[(wg0 + grow) * (L_OBS * 2) + 39];
  float posB0 = obs_pos[(wg0 + 16 + grow) * (L_OBS * 2) + 38];
  float posB1 = obs_pos[(wg0 + 16 + grow) * (L_OBS * 2) + 39];
  __syncthreads();
  const float ipA0 = ip_lds[grow][0],      ipA1 = ip_lds[grow][1];
  const float ipB0 = ip_lds[16 + grow][0], ipB1 = ip_lds[16 + grow][1];

  // ---- helpers ----
  auto MFMA_step = [&](const unsigned short* Ab, f32x4 (&acc)[4]) {
#pragma unroll
    for (int gt = 0; gt < 4; ++gt) { acc[gt].x = 0.f; acc[gt].y = 0.f; acc[gt].z = 0.f; acc[gt].w = 0.f; }
#pragma unroll
    for (int ks = 0; ks < 6; ++ks) {
      const bf16x8 a = *(const bf16x8*)&Ab[u15 * A_PAD + ks * 32 + rq * 8];
#pragma unroll
      for (int gt = 0; gt < 4; ++gt)
        acc[gt] = __builtin_amdgcn_mfma_f32_16x16x32_bf16(a, B[gt][ks], acc[gt], 0, 0, 0);
    }
  };

  auto gates = [&](f32x4 (&a4)[4], float (&cs_)[4], float (&hp_)[4], int sact_,
                   int j, bool domask, unsigned short* Ahdst) {
#pragma unroll
    for (int q = 0; q < 4; ++q) {
      const float A_ = ex2(fmaf(a4[0][q], -K1, nbi));
      const float F_ = ex2(fmaf(a4[1][q], -K1, nbf));
      const float B_ = ex2(fmaf(a4[2][q], -K2, nbg));
      const float C_ = ex2(fmaf(a4[3][q], -K1, nbo));
      const float P2 = 1.f + B_;
      const float PB = (1.f + A_) * P2;
      const float Q  = 1.f + F_;
      const float cn = fmaf(cs_[q], PB, (2.f - P2) * Q) * rcpn(PB * Q);
      const float cc = fmaxf(fminf(cn, 40.f), -40.f);
      const float D_ = ex2(-K2 * cc);
      const float hn = (1.f - D_) * rcpn((1.f + D_) * (1.f + C_));
      bool act = true;
      if (domask) act = j >= ((sact_ >> (8 * q)) & 255);
      if (act) { cs_[q] = cn; hp_[q] = hn; }
    }
    const unsigned int p01 = cvtpk(hp_[0], hp_[1]);
    const unsigned int p23 = cvtpk(hp_[2], hp_[3]);
    const int rowb = rq * 4;
    Ahdst[(rowb + 0) * A_PAD + 64 + u] = (unsigned short)p01;
    Ahdst[(rowb + 1) * A_PAD + 64 + u] = (unsigned short)(p01 >> 16);
    Ahdst[(rowb + 2) * A_PAD + 64 + u] = (unsigned short)p23;
    Ahdst[(rowb + 3) * A_PAD + 64 + u] = (unsigned short)(p23 >> 16);
  };

  auto e2write = [&](float r0, float r1, unsigned short* Ab) {
    const int j = c2 * 2;
    const float e0 = fmaxf(fmaf(r0, We_lds[0][j],     fmaf(r1, We_lds[1][j],     be_lds[j])),     0.f);
    const float e1 = fmaxf(fmaf(r0, We_lds[0][j + 1], fmaf(r1, We_lds[1][j + 1], be_lds[j + 1])), 0.f);
    *(unsigned int*)&Ab[grow * A_PAD + j] = cvtpk(e0, e1);
  };

  auto seg2 = [&](int X, int k, float& p0, float& p1, float ip0, float ip1) {
    unsigned short* Ab = &A_lds[X][k & 1][0][0];
    const s16x4 hv = *(const s16x4*)&Ab[grow * A_PAD + 64 + c2 * 4];
    float s0 = 0.f, s1 = 0.f;
#pragma unroll
    for (int i = 0; i < 4; ++i) {
      const float hf = bf2f((unsigned short)hv[i]);
      s0 = fmaf(hf, Wp_lds[c2 * 4 + i][0], s0);
      s1 = fmaf(hf, Wp_lds[c2 * 4 + i][1], s1);
    }
#pragma unroll
    for (int m = 16; m >= 1; m >>= 1) { s0 += __shfl_xor(s0, m); s1 += __shfl_xor(s1, m); }
    const float rel0 = s0 + ip0, rel1 = s1 + ip1;
    p0 += rel0; p1 += rel1;
    if (c2 == 0) {
      float2 o; o.x = p0; o.y = p1;
      *(float2*)&out[((long)(wg0 + X * 16 + grow) * P_PRED + (k - K_OBS)) * 2] = o;
    }
    if (k <= NSTEP - 2) e2write(rel0, rel1, Ab);
  };

  f32x4 accE[4], accO[4];   // pending gate inputs for G0 / G1

  // ================= phase-pair loop =================
#pragma unroll 1
  for (int phb = 0; phb < NSTEP; ++phb) {
    const int buf = phb & 1;
    // ---------- EVEN phase: MFMA(G0, phb) + gates(G1, phb-1) ----------
    {
      const int j = phb - 1;
      const bool pf = (phb >= 1 && phb <= K_OBS - 1);  // obs e for G1 step phb
      f32x2 rr;
      if (pf) rr = *(const f32x2*)(obs_rel + (wg0 + 16 + grow) * (L_OBS * 2) + (phb + 2) * 2);
      if (phb <= NSTEP - 2) MFMA_step(&A_lds[0][buf][0][0], accE);
      if (j >= 0) gates(accO, cs1, hp1, sact1, j, j < K_OBS, &A_lds[1][buf][0][0]);
      if (pf) e2write(rr.x, rr.y, &A_lds[1][buf][0][0]);
      __syncthreads();
      if (phb >= K_OBS) {
        seg2(1, phb, posB0, posB1, ipB0, ipB1);
        __syncthreads();
      }
    }
    // ---------- ODD phase: MFMA(G1, phb) + gates(G0, phb) ----------
    {
      const int j = phb;
      const bool pf = (phb + 1 <= K_OBS - 1);          // obs e for G0 step phb+1
      f32x2 rr;
      if (pf) rr = *(const f32x2*)(obs_rel + (wg0 + grow) * (L_OBS * 2) + (phb + 3) * 2);
      if (phb <= NSTEP - 2) MFMA_step(&A_lds[1][buf][0][0], accO);
      if (j <= NSTEP - 2) gates(accE, cs0, hp0, sact0, j, j < K_OBS, &A_lds[0][buf ^ 1][0][0]);
      if (pf) e2write(rr.x, rr.y, &A_lds[0][buf ^ 1][0][0]);
      __syncthreads();
      if (phb + 1 >= K_OBS && phb + 1 <= NSTEP - 1) {
        seg2(0, phb + 1, posA0, posA1, ipA0, ipA1);
        __syncthreads();
      }
    }
  }
}

extern "C" void kernel_launch(void* const* d_in, const int* in_sizes, int n_in,
                              void* d_out, int out_size, void* d_ws, size_t ws_size,
                              hipStream_t stream) {
  (void)in_sizes; (void)n_in; (void)out_size; (void)d_ws; (void)ws_size;
  lstm_traj<<<dim3(N_TOT / 32), dim3(NTH), 0, stream>>>(
      (const float*)d_in[0],  // img_embedding
      (const float*)d_in[1],  // obs_pos
      (const float*)d_in[2],  // obs_pos_rel
      (const int*)  d_in[3],  // obs_hist_size
      (const float*)d_in[4],  // h0
      (const float*)d_in[5],  // W_embed
      (const float*)d_in[6],  // b_embed
      (const float*)d_in[7],  // W_ih
      (const float*)d_in[8],  // W_hh
      (const float*)d_in[9],  // b_ih
      (const float*)d_in[10], // b_hh
      (const float*)d_in[11], // W_pred
      (const float*)d_in[12], // b_pred
      (float*)d_out);
}